// Round 2
// baseline (268.354 us; speedup 1.0000x reference)
//
#include <hip/hip_runtime.h>
#include <hip/hip_bf16.h>

using short8  = __attribute__((ext_vector_type(8))) short;
using f32x4   = __attribute__((ext_vector_type(4))) float;

#if __has_builtin(__builtin_amdgcn_exp2f)
#define EXP2(x) __builtin_amdgcn_exp2f(x)
#else
#define EXP2(x) __expf(0.6931471805599453f*(x))
#endif

__device__ __forceinline__ unsigned short f2bf(float x){
  union { float f; unsigned u; } c; c.f = x;
  unsigned u = c.u + 0x7FFFu + ((c.u >> 16) & 1u);
  return (unsigned short)(u >> 16);
}

__device__ __forceinline__ unsigned pack_bf16_rn(float a, float b){
  __hip_bfloat162 t = __float22bfloat162_rn(make_float2(a, b));
  unsigned u; __builtin_memcpy(&u, &t, 4);
  return u;
}

// ---------------- fused prep: dtype conversions + mask bit-pack ----------------
// bid < 8192: bf16 conversions (X, Wq*log2e/8, Wk, Wv, Wo)
// bid in [8192,12288): mask -> 1 bit/key via ballot. Row (b*2048+q) -> 32 u64 words.
__global__ __launch_bounds__(256) void prep(const float* __restrict__ X, const int* __restrict__ Mk,
                                            const float* __restrict__ Wq, const float* __restrict__ Wk,
                                            const float* __restrict__ Wv, const float* __restrict__ Wo,
                                            unsigned short* __restrict__ Xb, unsigned short* __restrict__ Wqkv,
                                            unsigned short* __restrict__ Wob, unsigned long long* __restrict__ Mbits)
{
  const int bid = blockIdx.x, tid = threadIdx.x;
  if (bid < 8192){
    const float* src; unsigned short* dst; float scale; int i;
    if (bid < 4096)      { src = X;  dst = Xb;             scale = 1.0f;          i = bid*1024 + tid*4; }
    else if (bid < 5120) { src = Wq; dst = Wqkv;           scale = 0.18033688f;   i = (bid-4096)*1024 + tid*4; } // 1/8 * log2(e)
    else if (bid < 6144) { src = Wk; dst = Wqkv + 1048576; scale = 1.0f;          i = (bid-5120)*1024 + tid*4; }
    else if (bid < 7168) { src = Wv; dst = Wqkv + 2097152; scale = 1.0f;          i = (bid-6144)*1024 + tid*4; }
    else                 { src = Wo; dst = Wob;            scale = 1.0f;          i = (bid-7168)*1024 + tid*4; }
    float4 v = *(const float4*)(src + i);
    ushort4 o;
    o.x = f2bf(v.x * scale); o.y = f2bf(v.y * scale);
    o.z = f2bf(v.z * scale); o.w = f2bf(v.w * scale);
    *(ushort4*)(dst + i) = o;
  } else {
    // one block per mask row; wave w covers keys [w*512, w*512+512)
    int row = bid - 8192;                       // 0..4095 = b*2048+q
    const int* src = Mk + (size_t)row * 2048;
    unsigned long long* dst = Mbits + (size_t)row * 32;
    int w = tid >> 6, l = tid & 63;
    #pragma unroll
    for (int p = 0; p < 8; p++){
      int v = src[w*512 + p*64 + l];            // coalesced 256B per ballot
      unsigned long long bm = __ballot(v != 0);
      if (l == 0) dst[w*8 + p] = bm;            // bit l of word = key w*512+p*64+l
    }
  }
}

// ---------------- async global->LDS, width 16 ----------------
__device__ __forceinline__ void stage16(const unsigned short* g, unsigned short* l){
  __builtin_amdgcn_global_load_lds(
      (const __attribute__((address_space(1))) void*)g,
      (__attribute__((address_space(3))) void*)l, 16, 0, 0);
}

// ---------------- gemm1: QKV = Xb * Wqkv^T; V-blocks write Vg transposed ----------
__global__ __launch_bounds__(256) void gemm_qkv(const unsigned short* __restrict__ A,
                                                const unsigned short* __restrict__ B,
                                                unsigned short* __restrict__ C,
                                                unsigned short* __restrict__ Vg)
{
  __shared__ unsigned short As[128*32];
  __shared__ unsigned short Bs[128*32];
  const int tid = threadIdx.x;
  const int wave = tid >> 6, lane = tid & 63, l16 = lane & 15, quad = lane >> 4;
  const int id = blockIdx.x, xcd = id & 7, m = id >> 3;
  const int bm = (m / 3) * 128, bn = (xcd * 3 + (m % 3)) * 128;
  const int wm = (wave >> 1) * 64, wn = (wave & 1) * 64;
  const int K = 1024;

  f32x4 acc[4][4] = {};
  for (int k0 = 0; k0 < K; k0 += 32){
    #pragma unroll
    for (int c = 0; c < 2; c++){
      int idx = c * 256 + tid;
      int row = idx >> 2, g = (idx & 3) * 8;
      stage16(A + (size_t)(bm + row) * K + k0 + g, &As[idx * 8]);
      stage16(B + (size_t)(bn + row) * K + k0 + g, &Bs[idx * 8]);
    }
    __syncthreads();
    short8 af[4], bf[4];
    #pragma unroll
    for (int i = 0; i < 4; i++) af[i] = *(const short8*)&As[(wm + i*16 + l16)*32 + quad*8];
    #pragma unroll
    for (int j = 0; j < 4; j++) bf[j] = *(const short8*)&Bs[(wn + j*16 + l16)*32 + quad*8];
    #pragma unroll
    for (int i = 0; i < 4; i++)
      #pragma unroll
      for (int j = 0; j < 4; j++)
        acc[i][j] = __builtin_amdgcn_mfma_f32_16x16x32_bf16(af[i], bf[j], acc[i][j], 0, 0, 0);
    __syncthreads();
  }

  if (bn < 2048){
    #pragma unroll
    for (int i = 0; i < 4; i++){
      int mrow = bm + wm + i*16 + quad*4;
      #pragma unroll
      for (int j = 0; j < 4; j++){
        int ncol = bn + wn + j*16 + l16;
        #pragma unroll
        for (int r = 0; r < 4; r++)
          C[(size_t)(mrow + r) * 3072 + ncol] = f2bf(acc[i][j][r]);
      }
    }
  } else {
    // write V transposed: Vg[bh][d][s], 4 s-consecutive bf16 per lane (8B store)
    #pragma unroll
    for (int i = 0; i < 4; i++){
      int srow = bm + wm + i*16 + quad*4;
      int b = srow >> 11, s = srow & 2047;
      #pragma unroll
      for (int j = 0; j < 4; j++){
        int c = bn - 2048 + wn + j*16 + l16;
        int h = c >> 6, d = c & 63;
        ushort4 o;
        o.x = f2bf(acc[i][j][0]); o.y = f2bf(acc[i][j][1]);
        o.z = f2bf(acc[i][j][2]); o.w = f2bf(acc[i][j][3]);
        *(ushort4*)&Vg[((size_t)(b*16 + h)*64 + d) * 2048 + s] = o;
      }
    }
  }
}

// ---------------- gemm2: out = Ob * Wob^T (f32 out), 128x64 tiles, XCD-swizzled ----
__global__ __launch_bounds__(256) void gemm_out(const unsigned short* __restrict__ A,
                                                const unsigned short* __restrict__ B,
                                                float* __restrict__ Cf)
{
  __shared__ unsigned short As[128*32];
  __shared__ unsigned short Bs[64*32];
  const int tid = threadIdx.x;
  const int wave = tid >> 6, lane = tid & 63, l16 = lane & 15, quad = lane >> 4;
  const int id = blockIdx.x, xcd = id & 7, m = id >> 3;
  const int bm = (m >> 1) * 128, bn = (xcd * 2 + (m & 1)) * 64;
  const int wm = (wave >> 1) * 64, wn = (wave & 1) * 32;
  const int K = 1024, N = 1024;

  f32x4 acc[4][2] = {};
  for (int k0 = 0; k0 < K; k0 += 32){
    #pragma unroll
    for (int c = 0; c < 2; c++){
      int idx = c * 256 + tid;
      int row = idx >> 2, g = (idx & 3) * 8;
      stage16(A + (size_t)(bm + row) * K + k0 + g, &As[idx * 8]);
    }
    stage16(B + (size_t)(bn + (tid >> 2)) * K + k0 + (tid & 3) * 8, &Bs[tid * 8]);
    __syncthreads();
    short8 af[4], bf[2];
    #pragma unroll
    for (int i = 0; i < 4; i++) af[i] = *(const short8*)&As[(wm + i*16 + l16)*32 + quad*8];
    #pragma unroll
    for (int j = 0; j < 2; j++) bf[j] = *(const short8*)&Bs[(wn + j*16 + l16)*32 + quad*8];
    #pragma unroll
    for (int i = 0; i < 4; i++)
      #pragma unroll
      for (int j = 0; j < 2; j++)
        acc[i][j] = __builtin_amdgcn_mfma_f32_16x16x32_bf16(af[i], bf[j], acc[i][j], 0, 0, 0);
    __syncthreads();
  }
  #pragma unroll
  for (int i = 0; i < 4; i++){
    int mrow = bm + wm + i*16 + quad*4;
    #pragma unroll
    for (int j = 0; j < 2; j++){
      int ncol = bn + wn + j*16 + l16;
      #pragma unroll
      for (int r = 0; r < 4; r++)
        Cf[(size_t)(mrow + r) * N + ncol] = acc[i][j][r];
    }
  }
}

// ---------------- attention: LDS-P, disjoint d-strips, bitmask, K=32 PV ---------
// Wave w: computes S^T strip (its 16 keys x 64 q), exp+cndmask+packs, writes P^T
// to LDS; then owns O^T d-strip [w*16, w*16+16) over ALL 64 keys of the chunk.
// Mask is 1 bit/key, prefetched 1 chunk ahead into registers (off critical path);
// per-XCD L2 footprint = K/V 2MB + mask 0.5MB < 4MB so chunk DMAs stay L2-hot.
// PV uses mfma_16x16x32 (8 MFMA + 10 ds_read_b128 per wave-chunk, was 16+20).
__global__ __launch_bounds__(256, 3) void attn(const unsigned short* __restrict__ QKV,
                                               const unsigned short* __restrict__ Vg,
                                               const unsigned short* __restrict__ mask16,
                                               unsigned short* __restrict__ O)
{
  __shared__ char smem[40960];
  unsigned short* Ks = (unsigned short*)smem;            // [2][64*64] 16 KB, xor-swizzled 16B blocks
  unsigned short* Vt = (unsigned short*)(smem + 16384);  // [2][64*64] 16 KB, [d][key] xor-swizzled
  unsigned short* Ps = (unsigned short*)(smem + 32768);  //  8 KB [q][key] bf16, xor-swizzled
  float* lsums = (float*)smem;                           // epilogue alias over dead Ks: [q][4] f32

  const int tid = threadIdx.x, wave = tid >> 6, lane = tid & 63;
  const int l16 = lane & 15, quad = lane >> 4;
  const int id = blockIdx.x;
  const int xcd = id & 7, m = id >> 3;         // round-robin XCD assumption
  const int bh = xcd * 4 + (m >> 5);           // 4 bh per XCD (K/V stay in this XCD's L2)
  const int qblk = (m & 31) * 64;
  const int b = bh >> 4, h = bh & 15;
  const unsigned short* Qg  = QKV + (size_t)b * 2048 * 3072 + h * 64;
  const unsigned short* Kg  = Qg + 1024;
  const unsigned short* Vgb = Vg + (size_t)bh * 64 * 2048;

  // per-nt bitmask row pointers: row = b*2048 + qblk + nt*16 + l16, this wave's
  // 16-key group at ushort offset c*4 + wave
  const unsigned short* mp[4];
  #pragma unroll
  for (int nt = 0; nt < 4; nt++)
    mp[nt] = mask16 + (size_t)(b*2048 + qblk + nt*16 + l16) * 128 + wave;

  // Q B-fragments resident in registers: B[n=q=l16][k=d=ks*32+quad*8+j]
  short8 qf[4][2];
  #pragma unroll
  for (int nt = 0; nt < 4; nt++)
    #pragma unroll
    for (int ks = 0; ks < 2; ks++)
      qf[nt][ks] = *(const short8*)(Qg + (size_t)(qblk + nt*16 + l16) * 3072 + ks*32 + quad*8);

  f32x4 oacc[4] = {};               // O^T strip: d = wave*16+quad*4+r, q = nt*16+l16
  float plsum[4] = {0.f, 0.f, 0.f, 0.f};
  const int sw = l16 & 7;

  // prologue: stage chunk 0 into buffer 0; load chunk-0 mask bits
  #pragma unroll
  for (int it = 0; it < 2; it++){
    int s = it * 256 + tid;
    int row = s >> 3, bg = (s & 7) ^ (row & 7);
    stage16(Kg + (size_t)row * 3072 + bg * 8, Ks + s * 8);
    stage16(Vgb + (size_t)row * 2048 + bg * 8, Vt + s * 8);
  }
  unsigned mcur[4], mnxt[4] = {0u, 0u, 0u, 0u};
  #pragma unroll
  for (int nt = 0; nt < 4; nt++) mcur[nt] = mp[nt][0];

  for (int c = 0; c < 32; c++){
    const int j0 = c * 64;
    const int buf = (c & 1) * 4096;
    __syncthreads();   // A: chunk-c DMAs + mask regs landed (vmcnt), prev PV's Ps reads done (lgkm)

    // issue next chunk's DMAs + mask prefetch; they fly through QK+PV, drained at next A
    if (c < 31){
      const int nj = j0 + 64, nbuf = ((c + 1) & 1) * 4096;
      #pragma unroll
      for (int it = 0; it < 2; it++){
        int s = it * 256 + tid;
        int row = s >> 3, bg = (s & 7) ^ (row & 7);
        stage16(Kg + (size_t)(nj + row) * 3072 + bg * 8, Ks + nbuf + s * 8);
        stage16(Vgb + (size_t)row * 2048 + nj + bg * 8, Vt + nbuf + s * 8);
      }
      #pragma unroll
      for (int nt = 0; nt < 4; nt++) mnxt[nt] = mp[nt][(c + 1) * 4];
    }

    // S^T = K * Q^T for this wave's 16 keys; exp; mask-select 1.0; pack; P^T to LDS
    short8 kf0 = *(const short8*)&Ks[buf + (wave*16 + l16) * 64 + ((0 + quad) ^ sw) * 8];
    short8 kf1 = *(const short8*)&Ks[buf + (wave*16 + l16) * 64 + ((4 + quad) ^ sw) * 8];
    #pragma unroll
    for (int nt = 0; nt < 4; nt++){
      f32x4 a = {0.f, 0.f, 0.f, 0.f};
      __builtin_amdgcn_s_setprio(1);
      a = __builtin_amdgcn_mfma_f32_16x16x32_bf16(kf0, qf[nt][0], a, 0, 0, 0);
      a = __builtin_amdgcn_mfma_f32_16x16x32_bf16(kf1, qf[nt][1], a, 0, 0, 0);
      __builtin_amdgcn_s_setprio(0);
      // scores in log2 domain (log2e folded into Wq); masked -> select 1.0 (=exp(-1e-9))
      float p0 = EXP2(a[0]);
      float p1 = EXP2(a[1]);
      float p2 = EXP2(a[2]);
      float p3 = EXP2(a[3]);
      unsigned mq = mcur[nt] >> (quad << 2);
      p0 = (mq & 1u) ? p0 : 1.0f;
      p1 = (mq & 2u) ? p1 : 1.0f;
      p2 = (mq & 4u) ? p2 : 1.0f;
      p3 = (mq & 8u) ? p3 : 1.0f;
      plsum[nt] += (p0 + p1) + (p2 + p3);
      uint2 st; st.x = pack_bf16_rn(p0, p1); st.y = pack_bf16_rn(p2, p3);
      // Ps[q = nt*16+l16][keys wave*16+quad*4 .. +3], xor-swizzled 16B blocks
      *(uint2*)&Ps[(nt*16 + l16) * 64 + ((wave*2 + (quad >> 1)) ^ sw) * 8 + (quad & 1) * 4] = st;
    }

    // B: P^T ready. LDS-only wait + raw barrier (does NOT drain the c+1 DMAs).
    __asm__ volatile("s_waitcnt lgkmcnt(0)" ::: "memory");
    __builtin_amdgcn_s_barrier();
    __builtin_amdgcn_sched_barrier(0);

    // O^T strip += V^T * P^T over all 64 keys: 2 k-steps of 32 (K=32 MFMA, b128 reads)
    #pragma unroll
    for (int kk = 0; kk < 2; kk++){
      short8 vfrag = *(const short8*)&Vt[buf + (wave*16 + l16) * 64 + ((kk*4 + quad) ^ sw) * 8];
      short8 pf[4];
      #pragma unroll
      for (int nt = 0; nt < 4; nt++)
        pf[nt] = *(const short8*)&Ps[(nt*16 + l16) * 64 + ((kk*4 + quad) ^ sw) * 8];
      __builtin_amdgcn_s_setprio(1);
      #pragma unroll
      for (int nt = 0; nt < 4; nt++)
        oacc[nt] = __builtin_amdgcn_mfma_f32_16x16x32_bf16(vfrag, pf[nt], oacc[nt], 0, 0, 0);
      __builtin_amdgcn_s_setprio(0);
    }

    #pragma unroll
    for (int nt = 0; nt < 4; nt++) mcur[nt] = mnxt[nt];
  }

  // ---- epilogue: lsum cross-wave reduce via LDS; disjoint O store (no O reduce) ----
  float lw[4];
  #pragma unroll
  for (int nt = 0; nt < 4; nt++){
    float v = plsum[nt];
    v += __shfl_xor(v, 16);
    v += __shfl_xor(v, 32);
    lw[nt] = v;
  }
  __syncthreads();                   // PV ds_reads done; Ks dead -> lsums alias safe
  if (quad == 0){
    #pragma unroll
    for (int nt = 0; nt < 4; nt++) lsums[(nt*16 + l16) * 4 + wave] = lw[nt];
  }
  __syncthreads();
  float linv[4];
  #pragma unroll
  for (int nt = 0; nt < 4; nt++){
    f32x4 ls = *(const f32x4*)&lsums[(nt*16 + l16) * 4];
    linv[nt] = 1.0f / (ls[0] + ls[1] + ls[2] + ls[3]);
  }
  #pragma unroll
  for (int nt = 0; nt < 4; nt++){
    f32x4 t = oacc[nt];
    unsigned u0 = pack_bf16_rn(t[0] * linv[nt], t[1] * linv[nt]);
    unsigned u1 = pack_bf16_rn(t[2] * linv[nt], t[3] * linv[nt]);
    uint2 st; st.x = u0; st.y = u1;
    *(uint2*)&O[(size_t)(b*2048 + qblk + nt*16 + l16) * 1024 + h*64 + wave*16 + quad*4] = st;
  }
}

// ---------------- launch ----------------
extern "C" void kernel_launch(void* const* d_in, const int* in_sizes, int n_in,
                              void* d_out, int out_size, void* d_ws, size_t ws_size,
                              hipStream_t stream)
{
  const float* X  = (const float*)d_in[0];
  const int*   Mk = (const int*)d_in[1];
  const float* Wq = (const float*)d_in[2];
  const float* Wk = (const float*)d_in[3];
  const float* Wv = (const float*)d_in[4];
  const float* Wo = (const float*)d_in[5];
  float* out = (float*)d_out;

  char* ws = (char*)d_ws;
  unsigned short* Xb   = (unsigned short*)(ws + 0);          //  8 MB  [4096][1024]
  unsigned short* Wqkv = (unsigned short*)(ws + 8388608);    //  6 MB  [3072][1024]
  unsigned short* Wob  = (unsigned short*)(ws + 14680064);   //  2 MB  [1024][1024]
  unsigned short* QKV  = (unsigned short*)(ws + 16777216);   // 24 MB  [4096][3072] (V cols unused)
  unsigned short* Ob   = (unsigned short*)(ws + 41943040);   //  8 MB  [4096][1024]
  unsigned long long* Mb = (unsigned long long*)(ws + 50331648); // 1 MB [4096][32] u64 bitmask
  unsigned short* Vg   = (unsigned short*)(ws + 58720256);   //  8 MB  [32][64][2048]

  prep<<<12288, 256, 0, stream>>>(X, Mk, Wq, Wk, Wv, Wo, Xb, Wqkv, Wob, Mb);
  gemm_qkv<<<768, 256, 0, stream>>>(Xb, Wqkv, QKV, Vg);
  attn<<<1024, 256, 0, stream>>>(QKV, Vg, (const unsigned short*)Mb, Ob);
  gemm_out<<<512, 256, 0, stream>>>(Ob, Wob, out);
}

// Round 3
// 267.061 us; speedup vs baseline: 1.0048x; 1.0048x over previous
//
#include <hip/hip_runtime.h>
#include <hip/hip_bf16.h>

using short8  = __attribute__((ext_vector_type(8))) short;
using f32x4   = __attribute__((ext_vector_type(4))) float;

#if __has_builtin(__builtin_amdgcn_exp2f)
#define EXP2(x) __builtin_amdgcn_exp2f(x)
#else
#define EXP2(x) __expf(0.6931471805599453f*(x))
#endif

__device__ __forceinline__ unsigned short f2bf(float x){
  union { float f; unsigned u; } c; c.f = x;
  unsigned u = c.u + 0x7FFFu + ((c.u >> 16) & 1u);
  return (unsigned short)(u >> 16);
}

__device__ __forceinline__ unsigned pack_bf16_rn(float a, float b){
  __hip_bfloat162 t = __float22bfloat162_rn(make_float2(a, b));
  unsigned u; __builtin_memcpy(&u, &t, 4);
  return u;
}

// ---------------- fused prep: dtype conversions + mask bit-pack ----------------
// bid < 8192: bf16 conversions (X, Wq*log2e/8, Wk, Wv, Wo)
// bid in [8192,12288): mask -> 1 bit/key via ballot. Row (b*2048+q) -> 32 u64 words.
__global__ __launch_bounds__(256) void prep(const float* __restrict__ X, const int* __restrict__ Mk,
                                            const float* __restrict__ Wq, const float* __restrict__ Wk,
                                            const float* __restrict__ Wv, const float* __restrict__ Wo,
                                            unsigned short* __restrict__ Xb, unsigned short* __restrict__ Wqkv,
                                            unsigned short* __restrict__ Wob, unsigned long long* __restrict__ Mbits)
{
  const int bid = blockIdx.x, tid = threadIdx.x;
  if (bid < 8192){
    const float* src; unsigned short* dst; float scale; int i;
    if (bid < 4096)      { src = X;  dst = Xb;             scale = 1.0f;          i = bid*1024 + tid*4; }
    else if (bid < 5120) { src = Wq; dst = Wqkv;           scale = 0.18033688f;   i = (bid-4096)*1024 + tid*4; } // 1/8 * log2(e)
    else if (bid < 6144) { src = Wk; dst = Wqkv + 1048576; scale = 1.0f;          i = (bid-5120)*1024 + tid*4; }
    else if (bid < 7168) { src = Wv; dst = Wqkv + 2097152; scale = 1.0f;          i = (bid-6144)*1024 + tid*4; }
    else                 { src = Wo; dst = Wob;            scale = 1.0f;          i = (bid-7168)*1024 + tid*4; }
    float4 v = *(const float4*)(src + i);
    ushort4 o;
    o.x = f2bf(v.x * scale); o.y = f2bf(v.y * scale);
    o.z = f2bf(v.z * scale); o.w = f2bf(v.w * scale);
    *(ushort4*)(dst + i) = o;
  } else {
    // one block per mask row; wave w covers keys [w*512, w*512+512)
    int row = bid - 8192;                       // 0..4095 = b*2048+q
    const int* src = Mk + (size_t)row * 2048;
    unsigned long long* dst = Mbits + (size_t)row * 32;
    int w = tid >> 6, l = tid & 63;
    #pragma unroll
    for (int p = 0; p < 8; p++){
      int v = src[w*512 + p*64 + l];            // coalesced 256B per ballot
      unsigned long long bm = __ballot(v != 0);
      if (l == 0) dst[w*8 + p] = bm;            // bit l of word = key w*512+p*64+l
    }
  }
}

// ---------------- async global->LDS, width 16 ----------------
__device__ __forceinline__ void stage16(const unsigned short* g, unsigned short* l){
  __builtin_amdgcn_global_load_lds(
      (const __attribute__((address_space(1))) void*)g,
      (__attribute__((address_space(3))) void*)l, 16, 0, 0);
}

// ---------------- gemm1: QKV = Xb * Wqkv^T; V-blocks write Vg transposed ----------
__global__ __launch_bounds__(256) void gemm_qkv(const unsigned short* __restrict__ A,
                                                const unsigned short* __restrict__ B,
                                                unsigned short* __restrict__ C,
                                                unsigned short* __restrict__ Vg)
{
  __shared__ unsigned short As[128*32];
  __shared__ unsigned short Bs[128*32];
  const int tid = threadIdx.x;
  const int wave = tid >> 6, lane = tid & 63, l16 = lane & 15, quad = lane >> 4;
  const int id = blockIdx.x, xcd = id & 7, m = id >> 3;
  const int bm = (m / 3) * 128, bn = (xcd * 3 + (m % 3)) * 128;
  const int wm = (wave >> 1) * 64, wn = (wave & 1) * 64;
  const int K = 1024;

  f32x4 acc[4][4] = {};
  for (int k0 = 0; k0 < K; k0 += 32){
    #pragma unroll
    for (int c = 0; c < 2; c++){
      int idx = c * 256 + tid;
      int row = idx >> 2, g = (idx & 3) * 8;
      stage16(A + (size_t)(bm + row) * K + k0 + g, &As[idx * 8]);
      stage16(B + (size_t)(bn + row) * K + k0 + g, &Bs[idx * 8]);
    }
    __syncthreads();
    short8 af[4], bf[4];
    #pragma unroll
    for (int i = 0; i < 4; i++) af[i] = *(const short8*)&As[(wm + i*16 + l16)*32 + quad*8];
    #pragma unroll
    for (int j = 0; j < 4; j++) bf[j] = *(const short8*)&Bs[(wn + j*16 + l16)*32 + quad*8];
    #pragma unroll
    for (int i = 0; i < 4; i++)
      #pragma unroll
      for (int j = 0; j < 4; j++)
        acc[i][j] = __builtin_amdgcn_mfma_f32_16x16x32_bf16(af[i], bf[j], acc[i][j], 0, 0, 0);
    __syncthreads();
  }

  if (bn < 2048){
    #pragma unroll
    for (int i = 0; i < 4; i++){
      int mrow = bm + wm + i*16 + quad*4;
      #pragma unroll
      for (int j = 0; j < 4; j++){
        int ncol = bn + wn + j*16 + l16;
        #pragma unroll
        for (int r = 0; r < 4; r++)
          C[(size_t)(mrow + r) * 3072 + ncol] = f2bf(acc[i][j][r]);
      }
    }
  } else {
    // write V transposed: Vg[bh][d][s], 4 s-consecutive bf16 per lane (8B store)
    #pragma unroll
    for (int i = 0; i < 4; i++){
      int srow = bm + wm + i*16 + quad*4;
      int b = srow >> 11, s = srow & 2047;
      #pragma unroll
      for (int j = 0; j < 4; j++){
        int c = bn - 2048 + wn + j*16 + l16;
        int h = c >> 6, d = c & 63;
        ushort4 o;
        o.x = f2bf(acc[i][j][0]); o.y = f2bf(acc[i][j][1]);
        o.z = f2bf(acc[i][j][2]); o.w = f2bf(acc[i][j][3]);
        *(ushort4*)&Vg[((size_t)(b*16 + h)*64 + d) * 2048 + s] = o;
      }
    }
  }
}

// ---------------- gemm2: out = Ob * Wob^T (f32 out), 128x64 tiles, XCD-swizzled ----
__global__ __launch_bounds__(256) void gemm_out(const unsigned short* __restrict__ A,
                                                const unsigned short* __restrict__ B,
                                                float* __restrict__ Cf)
{
  __shared__ unsigned short As[128*32];
  __shared__ unsigned short Bs[64*32];
  const int tid = threadIdx.x;
  const int wave = tid >> 6, lane = tid & 63, l16 = lane & 15, quad = lane >> 4;
  const int id = blockIdx.x, xcd = id & 7, m = id >> 3;
  const int bm = (m >> 1) * 128, bn = (xcd * 2 + (m & 1)) * 64;
  const int wm = (wave >> 1) * 64, wn = (wave & 1) * 32;
  const int K = 1024, N = 1024;

  f32x4 acc[4][2] = {};
  for (int k0 = 0; k0 < K; k0 += 32){
    #pragma unroll
    for (int c = 0; c < 2; c++){
      int idx = c * 256 + tid;
      int row = idx >> 2, g = (idx & 3) * 8;
      stage16(A + (size_t)(bm + row) * K + k0 + g, &As[idx * 8]);
    }
    stage16(B + (size_t)(bn + (tid >> 2)) * K + k0 + (tid & 3) * 8, &Bs[tid * 8]);
    __syncthreads();
    short8 af[4], bf[2];
    #pragma unroll
    for (int i = 0; i < 4; i++) af[i] = *(const short8*)&As[(wm + i*16 + l16)*32 + quad*8];
    #pragma unroll
    for (int j = 0; j < 2; j++) bf[j] = *(const short8*)&Bs[(wn + j*16 + l16)*32 + quad*8];
    #pragma unroll
    for (int i = 0; i < 4; i++)
      #pragma unroll
      for (int j = 0; j < 2; j++)
        acc[i][j] = __builtin_amdgcn_mfma_f32_16x16x32_bf16(af[i], bf[j], acc[i][j], 0, 0, 0);
    __syncthreads();
  }
  #pragma unroll
  for (int i = 0; i < 4; i++){
    int mrow = bm + wm + i*16 + quad*4;
    #pragma unroll
    for (int j = 0; j < 2; j++){
      int ncol = bn + wn + j*16 + l16;
      #pragma unroll
      for (int r = 0; r < 4; r++)
        Cf[(size_t)(mrow + r) * N + ncol] = acc[i][j][r];
    }
  }
}

// ---------------- attention: LDS-P, disjoint d-strips, bitmask, K=32 PV ---------
// Wave w: computes S^T strip (its 16 keys x 64 q), exp+cndmask+packs, writes P^T
// to LDS; then owns O^T d-strip [w*16, w*16+16) over ALL 64 keys of the chunk.
// Mask is 1 bit/key, prefetched 1 chunk ahead into registers (off critical path).
// Occupancy: LDS 40960B x 4 blocks = exactly 160 KiB/CU; launch_bounds(256,4)
// makes all 4 blocks/CU co-resident (grid 1024 = 4/CU, single pass, no tail) --
// the kernel is latency/barrier-bound (Mfma 13% + VALU 35%), so residency 3->4
// is the lever, not issue-work reduction.
__global__ __launch_bounds__(256, 4) void attn(const unsigned short* __restrict__ QKV,
                                               const unsigned short* __restrict__ Vg,
                                               const unsigned short* __restrict__ mask16,
                                               unsigned short* __restrict__ O)
{
  __shared__ char smem[40960];
  unsigned short* Ks = (unsigned short*)smem;            // [2][64*64] 16 KB, xor-swizzled 16B blocks
  unsigned short* Vt = (unsigned short*)(smem + 16384);  // [2][64*64] 16 KB, [d][key] xor-swizzled
  unsigned short* Ps = (unsigned short*)(smem + 32768);  //  8 KB [q][key] bf16, xor-swizzled
  float* lsums = (float*)smem;                           // epilogue alias over dead Ks: [q][4] f32

  const int tid = threadIdx.x, wave = tid >> 6, lane = tid & 63;
  const int l16 = lane & 15, quad = lane >> 4;
  const int id = blockIdx.x;
  const int xcd = id & 7, m = id >> 3;         // round-robin XCD assumption
  const int bh = xcd * 4 + (m >> 5);           // 4 bh per XCD (K/V stay in this XCD's L2)
  const int qblk = (m & 31) * 64;
  const int b = bh >> 4, h = bh & 15;
  const unsigned short* Qg  = QKV + (size_t)b * 2048 * 3072 + h * 64;
  const unsigned short* Kg  = Qg + 1024;
  const unsigned short* Vgb = Vg + (size_t)bh * 64 * 2048;

  // per-nt bitmask row pointers: row = b*2048 + qblk + nt*16 + l16, this wave's
  // 16-key group at ushort offset c*4 + wave
  const unsigned short* mp[4];
  #pragma unroll
  for (int nt = 0; nt < 4; nt++)
    mp[nt] = mask16 + (size_t)(b*2048 + qblk + nt*16 + l16) * 128 + wave;

  // Q B-fragments resident in registers: B[n=q=l16][k=d=ks*32+quad*8+j]
  short8 qf[4][2];
  #pragma unroll
  for (int nt = 0; nt < 4; nt++)
    #pragma unroll
    for (int ks = 0; ks < 2; ks++)
      qf[nt][ks] = *(const short8*)(Qg + (size_t)(qblk + nt*16 + l16) * 3072 + ks*32 + quad*8);

  f32x4 oacc[4] = {};               // O^T strip: d = wave*16+quad*4+r, q = nt*16+l16
  float plsum[4] = {0.f, 0.f, 0.f, 0.f};
  const int sw = l16 & 7;

  // prologue: stage chunk 0 into buffer 0; load chunk-0 mask bits
  #pragma unroll
  for (int it = 0; it < 2; it++){
    int s = it * 256 + tid;
    int row = s >> 3, bg = (s & 7) ^ (row & 7);
    stage16(Kg + (size_t)row * 3072 + bg * 8, Ks + s * 8);
    stage16(Vgb + (size_t)row * 2048 + bg * 8, Vt + s * 8);
  }
  unsigned mcur[4], mnxt[4] = {0u, 0u, 0u, 0u};
  #pragma unroll
  for (int nt = 0; nt < 4; nt++) mcur[nt] = mp[nt][0];

  for (int c = 0; c < 32; c++){
    const int j0 = c * 64;
    const int buf = (c & 1) * 4096;
    __syncthreads();   // A: chunk-c DMAs + mask regs landed (vmcnt), prev PV's Ps reads done (lgkm)

    // issue next chunk's DMAs + mask prefetch; they fly through QK+PV, drained at next A
    if (c < 31){
      const int nj = j0 + 64, nbuf = ((c + 1) & 1) * 4096;
      #pragma unroll
      for (int it = 0; it < 2; it++){
        int s = it * 256 + tid;
        int row = s >> 3, bg = (s & 7) ^ (row & 7);
        stage16(Kg + (size_t)(nj + row) * 3072 + bg * 8, Ks + nbuf + s * 8);
        stage16(Vgb + (size_t)row * 2048 + nj + bg * 8, Vt + nbuf + s * 8);
      }
      #pragma unroll
      for (int nt = 0; nt < 4; nt++) mnxt[nt] = mp[nt][(c + 1) * 4];
    }

    // S^T = K * Q^T for this wave's 16 keys; exp; mask-select 1.0; pack; P^T to LDS
    short8 kf0 = *(const short8*)&Ks[buf + (wave*16 + l16) * 64 + ((0 + quad) ^ sw) * 8];
    short8 kf1 = *(const short8*)&Ks[buf + (wave*16 + l16) * 64 + ((4 + quad) ^ sw) * 8];
    #pragma unroll
    for (int nt = 0; nt < 4; nt++){
      f32x4 a = {0.f, 0.f, 0.f, 0.f};
      __builtin_amdgcn_s_setprio(1);
      a = __builtin_amdgcn_mfma_f32_16x16x32_bf16(kf0, qf[nt][0], a, 0, 0, 0);
      a = __builtin_amdgcn_mfma_f32_16x16x32_bf16(kf1, qf[nt][1], a, 0, 0, 0);
      __builtin_amdgcn_s_setprio(0);
      // scores in log2 domain (log2e folded into Wq); masked -> select 1.0 (=exp(-1e-9))
      float p0 = EXP2(a[0]);
      float p1 = EXP2(a[1]);
      float p2 = EXP2(a[2]);
      float p3 = EXP2(a[3]);
      unsigned mq = mcur[nt] >> (quad << 2);
      p0 = (mq & 1u) ? p0 : 1.0f;
      p1 = (mq & 2u) ? p1 : 1.0f;
      p2 = (mq & 4u) ? p2 : 1.0f;
      p3 = (mq & 8u) ? p3 : 1.0f;
      plsum[nt] += (p0 + p1) + (p2 + p3);
      uint2 st; st.x = pack_bf16_rn(p0, p1); st.y = pack_bf16_rn(p2, p3);
      // Ps[q = nt*16+l16][keys wave*16+quad*4 .. +3], xor-swizzled 16B blocks
      *(uint2*)&Ps[(nt*16 + l16) * 64 + ((wave*2 + (quad >> 1)) ^ sw) * 8 + (quad & 1) * 4] = st;
    }

    // B: P^T ready. LDS-only wait + raw barrier (does NOT drain the c+1 DMAs).
    __asm__ volatile("s_waitcnt lgkmcnt(0)" ::: "memory");
    __builtin_amdgcn_s_barrier();
    __builtin_amdgcn_sched_barrier(0);

    // O^T strip += V^T * P^T over all 64 keys: 2 k-steps of 32 (K=32 MFMA, b128 reads)
    #pragma unroll
    for (int kk = 0; kk < 2; kk++){
      short8 vfrag = *(const short8*)&Vt[buf + (wave*16 + l16) * 64 + ((kk*4 + quad) ^ sw) * 8];
      short8 pf[4];
      #pragma unroll
      for (int nt = 0; nt < 4; nt++)
        pf[nt] = *(const short8*)&Ps[(nt*16 + l16) * 64 + ((kk*4 + quad) ^ sw) * 8];
      __builtin_amdgcn_s_setprio(1);
      #pragma unroll
      for (int nt = 0; nt < 4; nt++)
        oacc[nt] = __builtin_amdgcn_mfma_f32_16x16x32_bf16(vfrag, pf[nt], oacc[nt], 0, 0, 0);
      __builtin_amdgcn_s_setprio(0);
    }

    #pragma unroll
    for (int nt = 0; nt < 4; nt++) mcur[nt] = mnxt[nt];
  }

  // ---- epilogue: lsum cross-wave reduce via LDS; disjoint O store (no O reduce) ----
  float lw[4];
  #pragma unroll
  for (int nt = 0; nt < 4; nt++){
    float v = plsum[nt];
    v += __shfl_xor(v, 16);
    v += __shfl_xor(v, 32);
    lw[nt] = v;
  }
  __syncthreads();                   // PV ds_reads done; Ks dead -> lsums alias safe
  if (quad == 0){
    #pragma unroll
    for (int nt = 0; nt < 4; nt++) lsums[(nt*16 + l16) * 4 + wave] = lw[nt];
  }
  __syncthreads();
  float linv[4];
  #pragma unroll
  for (int nt = 0; nt < 4; nt++){
    f32x4 ls = *(const f32x4*)&lsums[(nt*16 + l16) * 4];
    linv[nt] = 1.0f / (ls[0] + ls[1] + ls[2] + ls[3]);
  }
  #pragma unroll
  for (int nt = 0; nt < 4; nt++){
    f32x4 t = oacc[nt];
    unsigned u0 = pack_bf16_rn(t[0] * linv[nt], t[1] * linv[nt]);
    unsigned u1 = pack_bf16_rn(t[2] * linv[nt], t[3] * linv[nt]);
    uint2 st; st.x = u0; st.y = u1;
    *(uint2*)&O[(size_t)(b*2048 + qblk + nt*16 + l16) * 1024 + h*64 + wave*16 + quad*4] = st;
  }
}

// ---------------- launch ----------------
extern "C" void kernel_launch(void* const* d_in, const int* in_sizes, int n_in,
                              void* d_out, int out_size, void* d_ws, size_t ws_size,
                              hipStream_t stream)
{
  const float* X  = (const float*)d_in[0];
  const int*   Mk = (const int*)d_in[1];
  const float* Wq = (const float*)d_in[2];
  const float* Wk = (const float*)d_in[3];
  const float* Wv = (const float*)d_in[4];
  const float* Wo = (const float*)d_in[5];
  float* out = (float*)d_out;

  char* ws = (char*)d_ws;
  unsigned short* Xb   = (unsigned short*)(ws + 0);          //  8 MB  [4096][1024]
  unsigned short* Wqkv = (unsigned short*)(ws + 8388608);    //  6 MB  [3072][1024]
  unsigned short* Wob  = (unsigned short*)(ws + 14680064);   //  2 MB  [1024][1024]
  unsigned short* QKV  = (unsigned short*)(ws + 16777216);   // 24 MB  [4096][3072] (V cols unused)
  unsigned short* Ob   = (unsigned short*)(ws + 41943040);   //  8 MB  [4096][1024]
  unsigned long long* Mb = (unsigned long long*)(ws + 50331648); // 1 MB [4096][32] u64 bitmask
  unsigned short* Vg   = (unsigned short*)(ws + 58720256);   //  8 MB  [32][64][2048]

  prep<<<12288, 256, 0, stream>>>(X, Mk, Wq, Wk, Wv, Wo, Xb, Wqkv, Wob, Mb);
  gemm_qkv<<<768, 256, 0, stream>>>(Xb, Wqkv, QKV, Vg);
  attn<<<1024, 256, 0, stream>>>(QKV, Vg, (const unsigned short*)Mb, Ob);
  gemm_out<<<512, 256, 0, stream>>>(Ob, Wob, out);
}